// Round 6
// baseline (349.110 us; speedup 1.0000x reference)
//
#include <hip/hip_runtime.h>
#include <math.h>

#define B_ 16
#define S_ 2048
#define IN_DIM 128
#define E2 6
#define E_ 3
#define OUT_DIM 64

// ws layout:
//   [0, B*S*4 floats)  : h as float4 (x,y,z, sq=|h|^2)   = 524288 B
//   then 64 ints       : per batch {max_d2_bits, total, diag, vert}

// one wave per row: 64 lanes x float2 = 128 inputs. Block 0 also zeroes acc.
__global__ __launch_bounds__(256) void embed_kernel(
    const float* __restrict__ x, const float* __restrict__ w1,
    const float* __restrict__ b1, const float* __restrict__ w2,
    const float* __restrict__ b2, float* __restrict__ hws,
    int* __restrict__ acc)
{
    if (blockIdx.x == 0 && threadIdx.x < 64) acc[threadIdx.x] = 0;
    int wave = threadIdx.x >> 6;
    int lane = threadIdx.x & 63;
    int row  = blockIdx.x * 4 + wave;            // [0, B*S)
    const float2* x2 = (const float2*)(x + (size_t)row * IN_DIM);
    float2 xv = x2[lane];
    const float* w1a = w1 + (2 * lane) * E2;     // 12 contiguous floats
    float a[E2];
#pragma unroll
    for (int q = 0; q < E2; ++q)
        a[q] = xv.x * w1a[q] + xv.y * w1a[E2 + q];
#pragma unroll
    for (int q = 0; q < E2; ++q) {
#pragma unroll
        for (int off = 32; off >= 1; off >>= 1)
            a[q] += __shfl_xor(a[q], off, 64);
    }
    if (lane == 0) {
        float r[E2];
#pragma unroll
        for (int q = 0; q < E2; ++q) r[q] = fmaxf(a[q] + b1[q], 0.f);
        float h[E_];
#pragma unroll
        for (int e = 0; e < E_; ++e) {
            float s = b2[e];
#pragma unroll
            for (int q = 0; q < E2; ++q) s += r[q] * w2[q * E_ + e];
            h[e] = s;
        }
        float sq = h[0] * h[0] + h[1] * h[1] + h[2] * h[2];
        ((float4*)hws)[row] = make_float4(h[0], h[1], h[2], sq);
    }
}

// grid: B * 2 colBlocks * 32 rowSpans = 1024 blocks of 256.
// thread = 4 columns (stride 256); rows r0-1..r0+64 staged once in a 1 KB
// LDS tile and re-read via broadcast ds_read_b128 (in-order retire ->
// compiler pipelines lgkmcnt(N) under the VALU). launch_bounds(256,4)
// caps VGPR at 128 (round-5 lesson: unbounded hoisting -> 256 VGPR + spill).
// d2 = sq_r + sq_c - 2*dot (reference's own formula);
// d2 < thr2  <=>  sq_r - 2*dot < thr2 - sq_c.
__global__ __launch_bounds__(256, 4) void max_kernel(
    const float4* __restrict__ h4, int* __restrict__ acc)
{
    int bid = blockIdx.x;
    int b  = bid >> 6;
    int cb = (bid >> 5) & 1;
    int rb = bid & 31;
    int r0 = rb * 64;
    int c0 = cb * 1024;
    if (r0 > c0 + 1023) return;                  // row>col half: mirrored elsewhere
    const float4* hb = h4 + (size_t)b * S_;
    __shared__ float4 sh[64];
    if (threadIdx.x < 64) sh[threadIdx.x] = hb[r0 + threadIdx.x];
    float4 hj[4];
#pragma unroll
    for (int c = 0; c < 4; ++c) hj[c] = hb[c0 + c * 256 + threadIdx.x];
    __syncthreads();
    float mc[4] = {-1e30f, -1e30f, -1e30f, -1e30f};
    for (int k8 = 0; k8 < 64; k8 += 8) {
        float4 buf[8];
#pragma unroll
        for (int k = 0; k < 8; ++k) buf[k] = sh[k8 + k];     // broadcast, conflict-free
#pragma unroll
        for (int c = 0; c < 4; ++c)
#pragma unroll
            for (int k = 0; k < 8; ++k) {
                float dot = fmaf(hj[c].x, buf[k].x,
                            fmaf(hj[c].y, buf[k].y, hj[c].z * buf[k].z));
                mc[c] = fmaxf(mc[c], fmaf(-2.f, dot, buf[k].w));  // sq_r - 2 dot
            }
    }
    float m = fmaxf(fmaxf(mc[0] + hj[0].w, mc[1] + hj[1].w),
                    fmaxf(mc[2] + hj[2].w, mc[3] + hj[3].w));
    m = fmaxf(m, 0.f);                           // d2 >= 0
#pragma unroll
    for (int off = 32; off >= 1; off >>= 1)
        m = fmaxf(m, __shfl_xor(m, off, 64));
    __shared__ float wmax[4];
    int lane = threadIdx.x & 63, wave = threadIdx.x >> 6;
    if (lane == 0) wmax[wave] = m;
    __syncthreads();
    if (threadIdx.x == 0) {
        float mm = fmaxf(fmaxf(wmax[0], wmax[1]), fmaxf(wmax[2], wmax[3]));
        atomicMax(&acc[b * 4 + 0], __float_as_int(mm));  // d2>=0: int order == float order
    }
}

__global__ __launch_bounds__(256, 4) void stats_kernel(
    const float4* __restrict__ h4, const float* __restrict__ theta,
    int* __restrict__ acc)
{
    int bid = blockIdx.x;
    int b  = bid >> 6;
    int cb = (bid >> 5) & 1;
    int rb = bid & 31;
    int r0 = rb * 64;
    int c0 = cb * 1024;
    const float4* hb = h4 + (size_t)b * S_;
    __shared__ float4 sh[66];                    // sh[1+k] = row r0+k
    if (threadIdx.x < 66) {
        int r = r0 - 1 + threadIdx.x;
        r = r < 0 ? 0 : (r >= S_ ? S_ - 1 : r);
        sh[threadIdx.x] = hb[r];
    }
    float4 hj[4];
#pragma unroll
    for (int c = 0; c < 4; ++c) hj[c] = hb[c0 + c * 256 + threadIdx.x];
    __syncthreads();
    float maxd2 = __int_as_float(acc[b * 4 + 0]);
    float sig   = 1.f / (1.f + expf(-theta[0]));
    float thr2  = sig * sig * maxd2;
    float thrc[4];
#pragma unroll
    for (int c = 0; c < 4; ++c) thrc[c] = thr2 - hj[c].w;  // d2<thr2 <=> sq_r-2dot<thrc

    unsigned m0[4] = {0u,0u,0u,0u}, m1[4] = {0u,0u,0u,0u};
    for (int k8 = 0; k8 < 64; k8 += 8) {
        float4 buf[8];
#pragma unroll
        for (int k = 0; k < 8; ++k) buf[k] = sh[1 + k8 + k];   // broadcast
#pragma unroll
        for (int c = 0; c < 4; ++c) {
#pragma unroll
            for (int k = 0; k < 8; ++k) {
                float dot = fmaf(hj[c].x, buf[k].x,
                            fmaf(hj[c].y, buf[k].y, hj[c].z * buf[k].z));
                unsigned r = (fmaf(-2.f, dot, buf[k].w) < thrc[c]) ? 1u : 0u;
                int bit = k8 + k;
                if (bit < 32) m0[c] |= r << bit;
                else          m1[c] |= r << (bit - 32);
            }
        }
    }

    int total = 0, diag = 0, vert = 0;
#pragma unroll
    for (int c = 0; c < 4; ++c) {
        int j = c0 + c * 256 + threadIdx.x;
        unsigned long long m = ((unsigned long long)m1[c] << 32) | m0[c];
        total += __popcll(m);
        float4 pr = sh[0], nx = sh[65];
        float dotp = fmaf(hj[c].x, pr.x, fmaf(hj[c].y, pr.y, hj[c].z * pr.z));
        float dotn = fmaf(hj[c].x, nx.x, fmaf(hj[c].y, nx.y, hj[c].z * nx.z));
        unsigned long long prevbit =
            (r0 > 0) ? ((fmaf(-2.f, dotp, pr.w) < thrc[c]) ? 1ull : 0ull) : 0ull;
        unsigned long long nextbit =
            (r0 + 64 < S_) ? ((fmaf(-2.f, dotn, nx.w) < thrc[c]) ? 1ull : 0ull) : 0ull;
        // vertical run starts: R[i] & ~R[i-1] & R[i+1]
        unsigned long long notprev = ~((m << 1) | prevbit);
        vert += __popcll(m & notprev & ((m >> 1) | (nextbit << 63)));
        // diag band: rows s with j-s in [1,9] -> bits [j-9-r0, j-1-r0]
        int lo = j - 9 - r0, hi = j - 1 - r0;
        if (hi >= 0 && lo <= 63) {
            int l = lo < 0 ? 0 : lo;
            int h = hi > 63 ? 63 : hi;
            unsigned long long bandm = ((1ull << (h - l + 1)) - 1ull) << l;
            diag += __popcll(m & bandm);
        }
    }

#pragma unroll
    for (int off = 32; off >= 1; off >>= 1) {
        total += __shfl_xor(total, off, 64);
        diag  += __shfl_xor(diag,  off, 64);
        vert  += __shfl_xor(vert,  off, 64);
    }
    __shared__ int wsum[4][3];
    int lane = threadIdx.x & 63, wave = threadIdx.x >> 6;
    if (lane == 0) { wsum[wave][0] = total; wsum[wave][1] = diag; wsum[wave][2] = vert; }
    __syncthreads();
    if (threadIdx.x == 0) {
        int t = 0, d = 0, v = 0;
#pragma unroll
        for (int w = 0; w < 4; ++w) { t += wsum[w][0]; d += wsum[w][1]; v += wsum[w][2]; }
        atomicAdd(&acc[b * 4 + 1], t);
        atomicAdd(&acc[b * 4 + 2], d);
        atomicAdd(&acc[b * 4 + 3], v);
    }
}

__global__ void finalize_kernel(const int* __restrict__ acc,
    const float* __restrict__ w3, const float* __restrict__ b3,
    float* __restrict__ out)
{
    int idx = blockIdx.x * 256 + threadIdx.x;    // 0..1023
    if (idx >= B_ * OUT_DIM) return;
    int b = idx >> 6, o = idx & 63;
    float total = (float)acc[b * 4 + 1];
    float diag  = (float)acc[b * 4 + 2];
    float vert  = (float)acc[b * 4 + 3];
    float rr  = total / (float)(S_ * S_);
    float det = diag / (total + 1e-6f);
    float lam = vert / (total + 1e-6f);
    float entr = -total * logf(1.0f + 1e-6f);    // fp32 semantics (verified absmax 0.0)
    float r = b3[o] + rr  * w3[0 * OUT_DIM + o]
                    + det * w3[1 * OUT_DIM + o]
                    + lam * w3[2 * OUT_DIM + o]
                    + entr * w3[3 * OUT_DIM + o];
    out[idx] = fmaxf(r, 0.f);
}

extern "C" void kernel_launch(void* const* d_in, const int* in_sizes, int n_in,
                              void* d_out, int out_size, void* d_ws, size_t ws_size,
                              hipStream_t stream) {
    const float* x     = (const float*)d_in[0];
    const float* theta = (const float*)d_in[1];
    const float* w1    = (const float*)d_in[2];
    const float* b1    = (const float*)d_in[3];
    const float* w2    = (const float*)d_in[4];
    const float* b2    = (const float*)d_in[5];
    const float* w3    = (const float*)d_in[6];
    const float* b3    = (const float*)d_in[7];
    float* out = (float*)d_out;
    float* hws = (float*)d_ws;
    int* acc = (int*)((char*)d_ws + (size_t)B_ * S_ * 4 * sizeof(float));

    hipLaunchKernelGGL(embed_kernel, dim3(B_ * S_ / 4), dim3(256), 0, stream,
                       x, w1, b1, w2, b2, hws, acc);
    hipLaunchKernelGGL(max_kernel, dim3(B_ * 64), dim3(256), 0, stream,
                       (const float4*)hws, acc);
    hipLaunchKernelGGL(stats_kernel, dim3(B_ * 64), dim3(256), 0, stream,
                       (const float4*)hws, theta, acc);
    hipLaunchKernelGGL(finalize_kernel, dim3(4), dim3(256), 0, stream, acc, w3, b3, out);
}

// Round 7
// 122.690 us; speedup vs baseline: 2.8455x; 2.8455x over previous
//
#include <hip/hip_runtime.h>
#include <math.h>

#define B_ 16
#define S_ 2048
#define IN_DIM 128
#define E2 6
#define E_ 3
#define OUT_DIM 64

// ws layout:
//   [0, B*S*4 floats)  : h as float4 (x,y,z, sq=|h|^2)   = 524288 B
//   then 64 ints       : per batch {max_d2_bits, total, diag, vert}
//
// Register-pressure rule learned R5/R6: NO manually-staged row arrays
// (buf[8] spilled to scratch -> 700 MB traffic). Rows are read from LDS
// one at a time (live range = 4 VGPRs), partial unroll only.

// one wave per row: 64 lanes x float2 = 128 inputs. Block 0 also zeroes acc.
__global__ __launch_bounds__(256) void embed_kernel(
    const float* __restrict__ x, const float* __restrict__ w1,
    const float* __restrict__ b1, const float* __restrict__ w2,
    const float* __restrict__ b2, float* __restrict__ hws,
    int* __restrict__ acc)
{
    if (blockIdx.x == 0 && threadIdx.x < 64) acc[threadIdx.x] = 0;
    int wave = threadIdx.x >> 6;
    int lane = threadIdx.x & 63;
    int row  = blockIdx.x * 4 + wave;            // [0, B*S)
    const float2* x2 = (const float2*)(x + (size_t)row * IN_DIM);
    float2 xv = x2[lane];
    const float* w1a = w1 + (2 * lane) * E2;     // 12 contiguous floats
    float a[E2];
#pragma unroll
    for (int q = 0; q < E2; ++q)
        a[q] = xv.x * w1a[q] + xv.y * w1a[E2 + q];
#pragma unroll
    for (int q = 0; q < E2; ++q) {
#pragma unroll
        for (int off = 32; off >= 1; off >>= 1)
            a[q] += __shfl_xor(a[q], off, 64);
    }
    if (lane == 0) {
        float r[E2];
#pragma unroll
        for (int q = 0; q < E2; ++q) r[q] = fmaxf(a[q] + b1[q], 0.f);
        float h[E_];
#pragma unroll
        for (int e = 0; e < E_; ++e) {
            float s = b2[e];
#pragma unroll
            for (int q = 0; q < E2; ++q) s += r[q] * w2[q * E_ + e];
            h[e] = s;
        }
        float sq = h[0] * h[0] + h[1] * h[1] + h[2] * h[2];
        ((float4*)hws)[row] = make_float4(h[0], h[1], h[2], sq);
    }
}

// grid: B * 2 colBlocks * 32 rowSpans = 1024 blocks of 256.
// thread = 4 columns (stride 256); rows in a 1 KB LDS tile, read one row
// per iteration (broadcast ds_read_b128, conflict-free, tiny live range).
// d2 = sq_r + sq_c - 2*dot;  d2 < thr2  <=>  sq_r - 2*dot < thr2 - sq_c.
// Symmetry prune: row<=col half suffices for the max.
__global__ __launch_bounds__(256) void max_kernel(
    const float4* __restrict__ h4, int* __restrict__ acc)
{
    int bid = blockIdx.x;
    int b  = bid >> 6;
    int cb = (bid >> 5) & 1;
    int rb = bid & 31;
    int r0 = rb * 64;
    int c0 = cb * 1024;
    if (r0 > c0 + 1023) return;                  // row>col half: mirrored elsewhere
    const float4* hb = h4 + (size_t)b * S_;
    __shared__ float4 sh[64];
    if (threadIdx.x < 64) sh[threadIdx.x] = hb[r0 + threadIdx.x];
    float4 hj[4];
#pragma unroll
    for (int c = 0; c < 4; ++c) hj[c] = hb[c0 + c * 256 + threadIdx.x];
    __syncthreads();
    float mc[4] = {-1e30f, -1e30f, -1e30f, -1e30f};
#pragma unroll 4
    for (int k = 0; k < 64; ++k) {
        float4 rv = sh[k];                       // one row, 4 VGPRs live
#pragma unroll
        for (int c = 0; c < 4; ++c) {
            float dot = fmaf(hj[c].x, rv.x, fmaf(hj[c].y, rv.y, hj[c].z * rv.z));
            mc[c] = fmaxf(mc[c], fmaf(-2.f, dot, rv.w));   // sq_r - 2 dot
        }
    }
    float m = fmaxf(fmaxf(mc[0] + hj[0].w, mc[1] + hj[1].w),
                    fmaxf(mc[2] + hj[2].w, mc[3] + hj[3].w));
    m = fmaxf(m, 0.f);                           // d2 >= 0
#pragma unroll
    for (int off = 32; off >= 1; off >>= 1)
        m = fmaxf(m, __shfl_xor(m, off, 64));
    __shared__ float wmax[4];
    int lane = threadIdx.x & 63, wave = threadIdx.x >> 6;
    if (lane == 0) wmax[wave] = m;
    __syncthreads();
    if (threadIdx.x == 0) {
        float mm = fmaxf(fmaxf(wmax[0], wmax[1]), fmaxf(wmax[2], wmax[3]));
        atomicMax(&acc[b * 4 + 0], __float_as_int(mm));  // d2>=0: int order == float order
    }
}

__global__ __launch_bounds__(256) void stats_kernel(
    const float4* __restrict__ h4, const float* __restrict__ theta,
    int* __restrict__ acc)
{
    int bid = blockIdx.x;
    int b  = bid >> 6;
    int cb = (bid >> 5) & 1;
    int rb = bid & 31;
    int r0 = rb * 64;
    int c0 = cb * 1024;
    const float4* hb = h4 + (size_t)b * S_;
    __shared__ float4 sh[66];                    // sh[1+k] = row r0+k
    if (threadIdx.x < 66) {
        int r = r0 - 1 + threadIdx.x;
        r = r < 0 ? 0 : (r >= S_ ? S_ - 1 : r);
        sh[threadIdx.x] = hb[r];
    }
    float4 hj[4];
#pragma unroll
    for (int c = 0; c < 4; ++c) hj[c] = hb[c0 + c * 256 + threadIdx.x];
    __syncthreads();
    float maxd2 = __int_as_float(acc[b * 4 + 0]);
    float sig   = 1.f / (1.f + expf(-theta[0]));
    float thr2  = sig * sig * maxd2;
    float thrc[4];
#pragma unroll
    for (int c = 0; c < 4; ++c) thrc[c] = thr2 - hj[c].w;  // d2<thr2 <=> sq_r-2dot<thrc

    unsigned m0[4] = {0u,0u,0u,0u}, m1[4] = {0u,0u,0u,0u};
#pragma unroll 4
    for (int k = 0; k < 32; ++k) {
        float4 rv = sh[1 + k];
        unsigned bitk = 1u << k;
#pragma unroll
        for (int c = 0; c < 4; ++c) {
            float dot = fmaf(hj[c].x, rv.x, fmaf(hj[c].y, rv.y, hj[c].z * rv.z));
            m0[c] |= (fmaf(-2.f, dot, rv.w) < thrc[c]) ? bitk : 0u;
        }
    }
#pragma unroll 4
    for (int k = 0; k < 32; ++k) {
        float4 rv = sh[33 + k];
        unsigned bitk = 1u << k;
#pragma unroll
        for (int c = 0; c < 4; ++c) {
            float dot = fmaf(hj[c].x, rv.x, fmaf(hj[c].y, rv.y, hj[c].z * rv.z));
            m1[c] |= (fmaf(-2.f, dot, rv.w) < thrc[c]) ? bitk : 0u;
        }
    }

    int total = 0, diag = 0, vert = 0;
#pragma unroll
    for (int c = 0; c < 4; ++c) {
        int j = c0 + c * 256 + threadIdx.x;
        unsigned long long m = ((unsigned long long)m1[c] << 32) | m0[c];
        total += __popcll(m);
        float4 pr = sh[0], nx = sh[65];
        float dotp = fmaf(hj[c].x, pr.x, fmaf(hj[c].y, pr.y, hj[c].z * pr.z));
        float dotn = fmaf(hj[c].x, nx.x, fmaf(hj[c].y, nx.y, hj[c].z * nx.z));
        unsigned long long prevbit =
            (r0 > 0) ? ((fmaf(-2.f, dotp, pr.w) < thrc[c]) ? 1ull : 0ull) : 0ull;
        unsigned long long nextbit =
            (r0 + 64 < S_) ? ((fmaf(-2.f, dotn, nx.w) < thrc[c]) ? 1ull : 0ull) : 0ull;
        // vertical run starts: R[i] & ~R[i-1] & R[i+1]
        unsigned long long notprev = ~((m << 1) | prevbit);
        vert += __popcll(m & notprev & ((m >> 1) | (nextbit << 63)));
        // diag band: rows s with j-s in [1,9] -> bits [j-9-r0, j-1-r0]
        int lo = j - 9 - r0, hi = j - 1 - r0;
        if (hi >= 0 && lo <= 63) {
            int l = lo < 0 ? 0 : lo;
            int h = hi > 63 ? 63 : hi;
            unsigned long long bandm = ((1ull << (h - l + 1)) - 1ull) << l;
            diag += __popcll(m & bandm);
        }
    }

#pragma unroll
    for (int off = 32; off >= 1; off >>= 1) {
        total += __shfl_xor(total, off, 64);
        diag  += __shfl_xor(diag,  off, 64);
        vert  += __shfl_xor(vert,  off, 64);
    }
    __shared__ int wsum[4][3];
    int lane = threadIdx.x & 63, wave = threadIdx.x >> 6;
    if (lane == 0) { wsum[wave][0] = total; wsum[wave][1] = diag; wsum[wave][2] = vert; }
    __syncthreads();
    if (threadIdx.x == 0) {
        int t = 0, d = 0, v = 0;
#pragma unroll
        for (int w = 0; w < 4; ++w) { t += wsum[w][0]; d += wsum[w][1]; v += wsum[w][2]; }
        atomicAdd(&acc[b * 4 + 1], t);
        atomicAdd(&acc[b * 4 + 2], d);
        atomicAdd(&acc[b * 4 + 3], v);
    }
}

__global__ void finalize_kernel(const int* __restrict__ acc,
    const float* __restrict__ w3, const float* __restrict__ b3,
    float* __restrict__ out)
{
    int idx = blockIdx.x * 256 + threadIdx.x;    // 0..1023
    if (idx >= B_ * OUT_DIM) return;
    int b = idx >> 6, o = idx & 63;
    float total = (float)acc[b * 4 + 1];
    float diag  = (float)acc[b * 4 + 2];
    float vert  = (float)acc[b * 4 + 3];
    float rr  = total / (float)(S_ * S_);
    float det = diag / (total + 1e-6f);
    float lam = vert / (total + 1e-6f);
    float entr = -total * logf(1.0f + 1e-6f);    // fp32 semantics (verified absmax 0.0)
    float r = b3[o] + rr  * w3[0 * OUT_DIM + o]
                    + det * w3[1 * OUT_DIM + o]
                    + lam * w3[2 * OUT_DIM + o]
                    + entr * w3[3 * OUT_DIM + o];
    out[idx] = fmaxf(r, 0.f);
}

extern "C" void kernel_launch(void* const* d_in, const int* in_sizes, int n_in,
                              void* d_out, int out_size, void* d_ws, size_t ws_size,
                              hipStream_t stream) {
    const float* x     = (const float*)d_in[0];
    const float* theta = (const float*)d_in[1];
    const float* w1    = (const float*)d_in[2];
    const float* b1    = (const float*)d_in[3];
    const float* w2    = (const float*)d_in[4];
    const float* b2    = (const float*)d_in[5];
    const float* w3    = (const float*)d_in[6];
    const float* b3    = (const float*)d_in[7];
    float* out = (float*)d_out;
    float* hws = (float*)d_ws;
    int* acc = (int*)((char*)d_ws + (size_t)B_ * S_ * 4 * sizeof(float));

    hipLaunchKernelGGL(embed_kernel, dim3(B_ * S_ / 4), dim3(256), 0, stream,
                       x, w1, b1, w2, b2, hws, acc);
    hipLaunchKernelGGL(max_kernel, dim3(B_ * 64), dim3(256), 0, stream,
                       (const float4*)hws, acc);
    hipLaunchKernelGGL(stats_kernel, dim3(B_ * 64), dim3(256), 0, stream,
                       (const float4*)hws, theta, acc);
    hipLaunchKernelGGL(finalize_kernel, dim3(4), dim3(256), 0, stream, acc, w3, b3, out);
}